// Round 1
// baseline (1025.793 us; speedup 1.0000x reference)
//
#include <hip/hip_runtime.h>

#define DF 64
#define MSG 20
#define HID2 10
#define NODES 50000
#define EDGES 800000
#define GRAPHS 512

__global__ void zero_kernel(float* __restrict__ p, int n) {
    int i = blockIdx.x * blockDim.x + threadIdx.x;
    int stride = gridDim.x * blockDim.x;
    for (; i < n; i += stride) p[i] = 0.0f;
}

// One thread per edge: gather src/dst node rows + edge row, 192->20 MLP, relu,
// atomic scatter-add into x1[dst].
__global__ __launch_bounds__(256) void edge_kernel(
    const int* __restrict__ ei,          // (2, E)
    const float* __restrict__ node_attr, // (N, 64)
    const float* __restrict__ edge_attr, // (E, 64)
    const float* __restrict__ W,         // (192, 20)
    const float* __restrict__ b,         // (20,)
    float* __restrict__ x1)              // (N, 20) accumulator
{
    int e = blockIdx.x * 256 + threadIdx.x;
    if (e >= EDGES) return;
    int src = ei[e];
    int dst = ei[EDGES + e];

    float acc[MSG];
#pragma unroll
    for (int j = 0; j < MSG; ++j) acc[j] = b[j];

    const float4* sr = (const float4*)(node_attr + (size_t)src * DF);
    const float4* dr = (const float4*)(node_attr + (size_t)dst * DF);
    const float4* er = (const float4*)(edge_attr + (size_t)e * DF);

    for (int k4 = 0; k4 < 16; ++k4) {
        float4 av = sr[k4];
        float4 bv = dr[k4];
        float4 cv = er[k4];
        const float* ap = (const float*)&av;
        const float* bp = (const float*)&bv;
        const float* cp = (const float*)&cv;
#pragma unroll
        for (int cc = 0; cc < 4; ++cc) {
            int k = k4 * 4 + cc;
            float a = ap[cc], bb = bp[cc], c = cp[cc];
#pragma unroll
            for (int j = 0; j < MSG; ++j) {
                float t = acc[j];
                t = fmaf(a,  W[k * MSG + j],            t);
                t = fmaf(bb, W[(DF + k) * MSG + j],     t);
                t = fmaf(c,  W[(2 * DF + k) * MSG + j], t);
                acc[j] = t;
            }
        }
    }

    float* xr = x1 + (size_t)dst * MSG;
#pragma unroll
    for (int j = 0; j < MSG; ++j) atomicAdd(xr + j, fmaxf(acc[j], 0.0f));
}

// One thread per node: 20 -> relu(W1) -> 20 -> relu(W2) -> 10, atomic into gacc[batch[n]].
__global__ __launch_bounds__(256) void node_kernel(
    const float* __restrict__ x1,  // (N, 20)
    const float* __restrict__ W1, const float* __restrict__ b1, // (20,20)
    const float* __restrict__ W2, const float* __restrict__ b2, // (20,10)
    const int* __restrict__ batch,
    float* __restrict__ gacc)      // (G, 10)
{
    int n = blockIdx.x * 256 + threadIdx.x;
    if (n >= NODES) return;

    float h[MSG];
    const float4* xr = (const float4*)(x1 + (size_t)n * MSG);
#pragma unroll
    for (int q = 0; q < 5; ++q) {
        float4 v = xr[q];
        h[q * 4 + 0] = v.x; h[q * 4 + 1] = v.y;
        h[q * 4 + 2] = v.z; h[q * 4 + 3] = v.w;
    }

    float t1[MSG];
#pragma unroll
    for (int j = 0; j < MSG; ++j) {
        float s = b1[j];
#pragma unroll
        for (int k = 0; k < MSG; ++k) s = fmaf(h[k], W1[k * MSG + j], s);
        t1[j] = fmaxf(s, 0.0f);
    }

    float t2[HID2];
#pragma unroll
    for (int m = 0; m < HID2; ++m) {
        float s = b2[m];
#pragma unroll
        for (int k = 0; k < MSG; ++k) s = fmaf(t1[k], W2[k * HID2 + m], s);
        t2[m] = fmaxf(s, 0.0f);
    }

    int g = batch[n];
    float* gr = gacc + (size_t)g * HID2;
#pragma unroll
    for (int m = 0; m < HID2; ++m) atomicAdd(gr + m, t2[m]);
}

// One thread per graph: 10 -> relu(W3) -> 10 -> W4 -> 1.
__global__ void graph_kernel(
    const float* __restrict__ gacc, // (G, 10)
    const float* __restrict__ W3, const float* __restrict__ b3, // (10,10)
    const float* __restrict__ W4, const float* __restrict__ b4, // (10,1)
    float* __restrict__ out)        // (G, 1)
{
    int g = blockIdx.x * blockDim.x + threadIdx.x;
    if (g >= GRAPHS) return;

    float h[HID2];
#pragma unroll
    for (int m = 0; m < HID2; ++m) h[m] = gacc[(size_t)g * HID2 + m];

    float t[HID2];
#pragma unroll
    for (int j = 0; j < HID2; ++j) {
        float s = b3[j];
#pragma unroll
        for (int k = 0; k < HID2; ++k) s = fmaf(h[k], W3[k * HID2 + j], s);
        t[j] = fmaxf(s, 0.0f);
    }

    float s = b4[0];
#pragma unroll
    for (int k = 0; k < HID2; ++k) s = fmaf(t[k], W4[k], s);
    out[g] = s;
}

extern "C" void kernel_launch(void* const* d_in, const int* in_sizes, int n_in,
                              void* d_out, int out_size, void* d_ws, size_t ws_size,
                              hipStream_t stream) {
    const int*   ei        = (const int*)  d_in[0];
    const float* node_attr = (const float*)d_in[1];
    const float* edge_attr = (const float*)d_in[2];
    const int*   batch     = (const int*)  d_in[3];
    const float* W_mpl     = (const float*)d_in[4];
    const float* b_mpl     = (const float*)d_in[5];
    const float* W1        = (const float*)d_in[6];
    const float* b1        = (const float*)d_in[7];
    const float* W2        = (const float*)d_in[8];
    const float* b2        = (const float*)d_in[9];
    const float* W3        = (const float*)d_in[10];
    const float* b3        = (const float*)d_in[11];
    const float* W4        = (const float*)d_in[12];
    const float* b4        = (const float*)d_in[13];
    float* out = (float*)d_out;

    float* x1   = (float*)d_ws;                  // N*20 floats
    float* gacc = x1 + (size_t)NODES * MSG;      // G*10 floats

    int ztot = NODES * MSG + GRAPHS * HID2;
    hipLaunchKernelGGL(zero_kernel, dim3(2048), dim3(256), 0, stream, x1, ztot);
    hipLaunchKernelGGL(edge_kernel, dim3((EDGES + 255) / 256), dim3(256), 0, stream,
                       ei, node_attr, edge_attr, W_mpl, b_mpl, x1);
    hipLaunchKernelGGL(node_kernel, dim3((NODES + 255) / 256), dim3(256), 0, stream,
                       x1, W1, b1, W2, b2, batch, gacc);
    hipLaunchKernelGGL(graph_kernel, dim3(2), dim3(256), 0, stream,
                       gacc, W3, b3, W4, b4, out);
}